// Round 3
// baseline (1500.750 us; speedup 1.0000x reference)
//
#include <hip/hip_runtime.h>

#define N_NODES 100000
#define N_FEAT  1433
#define KP      1472     // padded K: 46*32, 23*64
#define HID     64
#define NCLS    7

typedef __attribute__((ext_vector_type(8))) short short8v;
typedef __attribute__((ext_vector_type(4))) float f32x4;

__device__ __forceinline__ unsigned short f2bf(float v) {
    unsigned u = __float_as_uint(v);
    unsigned r = (u + 0x7FFFu + ((u >> 16) & 1u)) >> 16;   // RNE
    return (unsigned short)r;
}
__device__ __forceinline__ float bf2f(unsigned short h) {
    return __uint_as_float(((unsigned)h) << 16);
}

// ---------------- degree histogram ----------------
__global__ __launch_bounds__(256)
void hist_kernel(const int* __restrict__ dst, int* __restrict__ counts, int E) {
    int e = blockIdx.x * 256 + threadIdx.x;
    if (e < E) atomicAdd(&counts[dst[e]], 1);
}

__global__ __launch_bounds__(256)
void dinv_kernel(const int* __restrict__ counts, float* __restrict__ dinv, int n) {
    int i = blockIdx.x * 256 + threadIdx.x;
    if (i < n) dinv[i] = rsqrtf((float)(counts[i] + 1));   // +1 = self loop
}

// ---------------- single-block exclusive scan ----------------
__global__ __launch_bounds__(1024)
void scan_kernel(const int* __restrict__ counts, int* __restrict__ offsets,
                 int* __restrict__ cursor, int n) {
    __shared__ int sums[1024];
    int t = threadIdx.x;
    int chunk = (n + 1023) >> 10;
    int beg = t * chunk;
    int end = min(beg + chunk, n);
    int s = 0;
    for (int i = beg; i < end; ++i) s += counts[i];
    sums[t] = s;
    __syncthreads();
    for (int off = 1; off < 1024; off <<= 1) {
        int v = (t >= off) ? sums[t - off] : 0;
        __syncthreads();
        sums[t] += v;
        __syncthreads();
    }
    int run = (t == 0) ? 0 : sums[t - 1];
    for (int i = beg; i < end; ++i) {
        offsets[i] = run; cursor[i] = run;
        run += counts[i];
    }
    if (t == 1023) offsets[n] = run;
}

// ---------------- CSR scatter ----------------
__global__ __launch_bounds__(256)
void scatter_kernel(const int* __restrict__ src, const int* __restrict__ dst,
                    const float* __restrict__ dinv, int* __restrict__ cursor,
                    int* __restrict__ csr_src, float* __restrict__ csr_w, int E) {
    int e = blockIdx.x * 256 + threadIdx.x;
    if (e >= E) return;
    int s = src[e], d = dst[e];
    int pos = atomicAdd(&cursor[d], 1);
    csr_src[pos] = s;
    csr_w[pos]   = dinv[s] * dinv[d];
}

// ---------------- W1 transpose + bf16 hi/lo split: [1433,64] -> [64,KP] ----------------
__global__ __launch_bounds__(256)
void convert_w(const float* __restrict__ W,
               unsigned short* __restrict__ wt_hi, unsigned short* __restrict__ wt_lo) {
    int idx = blockIdx.x * 256 + threadIdx.x;   // over KP*64
    if (idx >= KP * 64) return;
    int k = idx >> 6, n = idx & 63;
    float v = (k < N_FEAT) ? W[(size_t)k * 64 + n] : 0.f;
    unsigned short h = f2bf(v);
    wt_hi[(size_t)n * KP + k] = h;
    wt_lo[(size_t)n * KP + k] = f2bf(v - bf2f(h));
}

// ---------------- X f32 -> bf16, row-padded to KP ----------------
__global__ __launch_bounds__(256)
void convert_x(const float* __restrict__ X, unsigned short* __restrict__ X16) {
    int row = blockIdx.x;
    const float* xr = X + (size_t)row * N_FEAT;
    unsigned short* o = X16 + (size_t)row * KP;
    for (int c = threadIdx.x; c < KP; c += 256) {
        float v = (c < N_FEAT) ? xr[c] : 0.f;
        o[c] = f2bf(v);
    }
}

// ---------------- GEMM1 v3: barrier-free, LDS-free MFMA ----------------
// Block = 4 waves; wave owns 32 rows (2x16). A direct from global bf16 (coalesced
// 128B lines), B direct from L2-resident wt_hi/wt_lo. No LDS, no __syncthreads.
__global__ __launch_bounds__(256)
void gemm_xw_v3(const unsigned short* __restrict__ X16,
                const unsigned short* __restrict__ wt_hi,
                const unsigned short* __restrict__ wt_lo,
                float* __restrict__ H, int M) {
    const int t    = threadIdx.x;
    const int lane = t & 63;
    const int w    = t >> 6;
    const int m0   = blockIdx.x * 128 + w * 32;
    const int lrow = lane & 15;
    const int koff = (lane >> 4) * 8;

    f32x4 acc[2][4];
#pragma unroll
    for (int i = 0; i < 2; ++i)
#pragma unroll
        for (int j = 0; j < 4; ++j) acc[i][j] = (f32x4){0.f, 0.f, 0.f, 0.f};

    const unsigned short* a0 = X16 + (size_t)min(m0 + lrow,      M - 1) * KP + koff;
    const unsigned short* a1 = X16 + (size_t)min(m0 + 16 + lrow, M - 1) * KP + koff;
    const unsigned short* bh = wt_hi + (size_t)lrow * KP + koff;
    const unsigned short* bl = wt_lo + (size_t)lrow * KP + koff;

#pragma unroll 2
    for (int k = 0; k < KP; k += 32) {
        short8v aH[2], bH[4], bL[4];
        aH[0] = *(const short8v*)(a0 + k);
        aH[1] = *(const short8v*)(a1 + k);
#pragma unroll
        for (int nf = 0; nf < 4; ++nf) {
            bH[nf] = *(const short8v*)(bh + (size_t)nf * 16 * KP + k);
            bL[nf] = *(const short8v*)(bl + (size_t)nf * 16 * KP + k);
        }
#pragma unroll
        for (int mf = 0; mf < 2; ++mf)
#pragma unroll
            for (int nf = 0; nf < 4; ++nf) {
                acc[mf][nf] = __builtin_amdgcn_mfma_f32_16x16x32_bf16(aH[mf], bH[nf], acc[mf][nf], 0, 0, 0);
                acc[mf][nf] = __builtin_amdgcn_mfma_f32_16x16x32_bf16(aH[mf], bL[nf], acc[mf][nf], 0, 0, 0);
            }
    }
    // C write: col = lane&15, row = (lane>>4)*4 + reg  [HW-verified layout]
#pragma unroll
    for (int mf = 0; mf < 2; ++mf)
#pragma unroll
        for (int r = 0; r < 4; ++r) {
            int row = m0 + mf * 16 + ((lane >> 4) << 2) + r;
            if (row < M) {
#pragma unroll
                for (int nf = 0; nf < 4; ++nf)
                    H[(size_t)row * 64 + nf * 16 + lrow] = acc[mf][nf][r];
            }
        }
}

// ---------------- GEMM1 fallback (round-2 fused version) for small ws ----------------
__global__ __launch_bounds__(256)
void gemm_xw_mfma(const float* __restrict__ X,
                  const unsigned short* __restrict__ wt_hi,
                  const unsigned short* __restrict__ wt_lo,
                  float* __restrict__ H, int M) {
    __shared__ __align__(16) unsigned short AsH[128 * 64];
    __shared__ __align__(16) unsigned short AsL[128 * 64];
    __shared__ __align__(16) unsigned short BsH[64 * 64];
    __shared__ __align__(16) unsigned short BsL[64 * 64];
    char* asH = (char*)AsH; char* asL = (char*)AsL;
    char* bsH = (char*)BsH; char* bsL = (char*)BsL;

    const int t    = threadIdx.x;
    const int m0   = blockIdx.x * 128;
    const int lane = t & 63;
    const int w    = t >> 6;

    f32x4 acc[2][4];
#pragma unroll
    for (int i = 0; i < 2; ++i)
#pragma unroll
        for (int j = 0; j < 4; ++j) acc[i][j] = (f32x4){0.f, 0.f, 0.f, 0.f};

    for (int k0 = 0; k0 < KP; k0 += 64) {
#pragma unroll
        for (int p = 0; p < 16; ++p) {
            int id  = p * 256 + t;
            int row = id >> 5;
            int kp  = id & 31;
            int grow = m0 + row;
            int k = k0 + kp * 2;
            float v0 = 0.f, v1 = 0.f;
            if (grow < M) {
                if (k < N_FEAT)     v0 = X[(size_t)grow * N_FEAT + k];
                if (k + 1 < N_FEAT) v1 = X[(size_t)grow * N_FEAT + k + 1];
            }
            unsigned short h0 = f2bf(v0), h1 = f2bf(v1);
            unsigned hi = (unsigned)h0 | ((unsigned)h1 << 16);
            unsigned lo = (unsigned)f2bf(v0 - bf2f(h0)) |
                          ((unsigned)f2bf(v1 - bf2f(h1)) << 16);
            int byte = (row * 128 + kp * 4) ^ ((row & 7) << 4);
            *(unsigned*)(asH + byte) = hi;
            *(unsigned*)(asL + byte) = lo;
        }
#pragma unroll
        for (int p = 0; p < 2; ++p) {
            int id = p * 256 + t;
            int n = id >> 3, k8 = id & 7;
            size_t g = (size_t)n * KP + k0 + k8 * 8;
            uint4 vh = *(const uint4*)(wt_hi + g);
            uint4 vl = *(const uint4*)(wt_lo + g);
            int byte = (n * 128 + k8 * 16) ^ ((n & 7) << 4);
            *(uint4*)(bsH + byte) = vh;
            *(uint4*)(bsL + byte) = vl;
        }
        __syncthreads();
#pragma unroll
        for (int kf = 0; kf < 2; ++kf) {
            int kb = kf * 64 + ((lane >> 4) << 4);
            short8v aH[2], aL[2], bH[4], bL[4];
#pragma unroll
            for (int mf = 0; mf < 2; ++mf) {
                int row = w * 32 + mf * 16 + (lane & 15);
                int byte = (row * 128 + kb) ^ ((row & 7) << 4);
                aH[mf] = *(short8v*)(asH + byte);
                aL[mf] = *(short8v*)(asL + byte);
            }
#pragma unroll
            for (int nf = 0; nf < 4; ++nf) {
                int n = nf * 16 + (lane & 15);
                int byte = (n * 128 + kb) ^ ((n & 7) << 4);
                bH[nf] = *(short8v*)(bsH + byte);
                bL[nf] = *(short8v*)(bsL + byte);
            }
#pragma unroll
            for (int mf = 0; mf < 2; ++mf)
#pragma unroll
                for (int nf = 0; nf < 4; ++nf) {
                    acc[mf][nf] = __builtin_amdgcn_mfma_f32_16x16x32_bf16(aH[mf], bH[nf], acc[mf][nf], 0, 0, 0);
                    acc[mf][nf] = __builtin_amdgcn_mfma_f32_16x16x32_bf16(aL[mf], bH[nf], acc[mf][nf], 0, 0, 0);
                    acc[mf][nf] = __builtin_amdgcn_mfma_f32_16x16x32_bf16(aH[mf], bL[nf], acc[mf][nf], 0, 0, 0);
                }
        }
        __syncthreads();
    }
#pragma unroll
    for (int mf = 0; mf < 2; ++mf)
#pragma unroll
        for (int r = 0; r < 4; ++r) {
            int row = m0 + w * 32 + mf * 16 + ((lane >> 4) << 2) + r;
            if (row < M) {
#pragma unroll
                for (int nf = 0; nf < 4; ++nf)
                    H[(size_t)row * 64 + nf * 16 + (lane & 15)] = acc[mf][nf][r];
            }
        }
}

// ---------------- gather-aggregate: one wave per node, lane = feature ----------------
__global__ __launch_bounds__(256)
void aggregate_kernel(const float* __restrict__ h, const int* __restrict__ csr_src,
                      const float* __restrict__ csr_w, const int* __restrict__ offsets,
                      const float* __restrict__ dinv, const float* __restrict__ bias,
                      float* __restrict__ out, int n) {
    int wave = (blockIdx.x * blockDim.x + threadIdx.x) >> 6;
    int lane = threadIdx.x & 63;
    if (wave >= n) return;
    float di  = dinv[wave];
    float acc = h[(size_t)wave * HID + lane] * di * di;   // self loop
    int e = offsets[wave], end = offsets[wave + 1];
    for (; e + 4 <= end; e += 4) {
        int   s0 = csr_src[e],   s1 = csr_src[e+1], s2 = csr_src[e+2], s3 = csr_src[e+3];
        float w0 = csr_w[e],     w1 = csr_w[e+1],   w2 = csr_w[e+2],   w3 = csr_w[e+3];
        float h0 = h[(size_t)s0 * HID + lane];
        float h1 = h[(size_t)s1 * HID + lane];
        float h2 = h[(size_t)s2 * HID + lane];
        float h3 = h[(size_t)s3 * HID + lane];
        acc = fmaf(h0, w0, acc); acc = fmaf(h1, w1, acc);
        acc = fmaf(h2, w2, acc); acc = fmaf(h3, w3, acc);
    }
    for (; e < end; ++e)
        acc = fmaf(h[(size_t)csr_src[e] * HID + lane], csr_w[e], acc);
    out[(size_t)wave * HID + lane] = fmaxf(acc + bias[lane], 0.f);
}

// ---------------- GEMM2: [M,64] @ [64,64], wave per row ----------------
__global__ __launch_bounds__(256)
void gemm64_kernel(const float* __restrict__ A, const float* __restrict__ W,
                   float* __restrict__ out, int M) {
    __shared__ float Ws[64 * 64];
    for (int i = threadIdx.x; i < 64 * 64; i += 256) Ws[i] = W[i];
    __syncthreads();
    int wave = (blockIdx.x * blockDim.x + threadIdx.x) >> 6;
    int lane = threadIdx.x & 63;
    if (wave >= M) return;
    const float* a = A + (size_t)wave * 64;
    float acc = 0.f;
#pragma unroll
    for (int k = 0; k < 64; ++k) acc = fmaf(a[k], Ws[k * 64 + lane], acc);
    out[(size_t)wave * 64 + lane] = acc;
}

// ---------------- fused MLP head + log_softmax: wave per node ----------------
__global__ __launch_bounds__(256)
void mlp_kernel(const float* __restrict__ y,
                const float* __restrict__ Wf1, const float* __restrict__ bf1,
                const float* __restrict__ Wf2, const float* __restrict__ bf2,
                const float* __restrict__ Wf3, const float* __restrict__ bf3,
                float* __restrict__ out, int M) {
    __shared__ float W1s[64 * 64];
    __shared__ float W2s[64 * 64];
    __shared__ float W3s[64 * NCLS];
    __shared__ float b1s[64], b2s[64], b3s[NCLS];
    __shared__ float vbuf[4][64];
    __shared__ float zbuf[4][8];
    int tid = threadIdx.x;
    for (int i = tid; i < 4096; i += 256) { W1s[i] = Wf1[i]; W2s[i] = Wf2[i]; }
    for (int i = tid; i < 64 * NCLS; i += 256) W3s[i] = Wf3[i];
    if (tid < 64) { b1s[tid] = bf1[tid]; b2s[tid] = bf2[tid]; }
    if (tid < NCLS) b3s[tid] = bf3[tid];
    __syncthreads();
    int w = tid >> 6, lane = tid & 63;
    int node = blockIdx.x * 4 + w;
    if (node >= M) return;

    vbuf[w][lane] = y[(size_t)node * 64 + lane];
    float u = b1s[lane];
#pragma unroll
    for (int k = 0; k < 64; ++k) u = fmaf(vbuf[w][k], W1s[k * 64 + lane], u);
    u = fmaxf(u, 0.f);
    vbuf[w][lane] = u;
    float u2 = b2s[lane];
#pragma unroll
    for (int k = 0; k < 64; ++k) u2 = fmaf(vbuf[w][k], W2s[k * 64 + lane], u2);
    u2 = fmaxf(u2, 0.f);
    vbuf[w][lane] = u2;
    float z = 0.f;
    if (lane < NCLS) {
        z = b3s[lane];
#pragma unroll
        for (int k = 0; k < 64; ++k) z = fmaf(vbuf[w][k], W3s[k * NCLS + lane], z);
    }
    if (lane < 8)    zbuf[w][lane] = -1e30f;
    if (lane < NCLS) zbuf[w][lane] = z;
    float m = -1e30f;
#pragma unroll
    for (int j = 0; j < NCLS; ++j) m = fmaxf(m, zbuf[w][j]);
    float ssum = 0.f;
#pragma unroll
    for (int j = 0; j < NCLS; ++j) ssum += expf(zbuf[w][j] - m);
    float lse = m + logf(ssum);
    if (lane < NCLS) out[(size_t)node * NCLS + lane] = z - lse;
}

extern "C" void kernel_launch(void* const* d_in, const int* in_sizes, int n_in,
                              void* d_out, int out_size, void* d_ws, size_t ws_size,
                              hipStream_t stream) {
    const float* x   = (const float*)d_in[0];
    const int*   ei  = (const int*)d_in[1];
    const float* W1  = (const float*)d_in[2];
    const float* b1  = (const float*)d_in[3];
    const float* W2  = (const float*)d_in[4];
    const float* b2  = (const float*)d_in[5];
    const float* Wf1 = (const float*)d_in[6];
    const float* bf1 = (const float*)d_in[7];
    const float* Wf2 = (const float*)d_in[8];
    const float* bf2 = (const float*)d_in[9];
    const float* Wf3 = (const float*)d_in[10];
    const float* bf3 = (const float*)d_in[11];

    const int N = N_NODES;
    const int E = in_sizes[1] / 2;
    float* outp = (float*)d_out;

    char* p = (char*)d_ws;
    size_t used = 0;
    auto alloc = [&](size_t bytes) {
        char* q = p;
        size_t a = (bytes + 255) & ~(size_t)255;
        p += a; used += a;
        return q;
    };
    int*            counts  = (int*)           alloc((size_t)N * 4);
    int*            offsets = (int*)           alloc((size_t)(N + 1) * 4);
    int*            cursor  = (int*)           alloc((size_t)N * 4);
    float*          dinv    = (float*)         alloc((size_t)N * 4);
    int*            csr_src = (int*)           alloc((size_t)E * 4);
    float*          csr_w   = (float*)         alloc((size_t)E * 4);
    float*          bufA    = (float*)         alloc((size_t)N * HID * 4);
    float*          bufB    = (float*)         alloc((size_t)N * HID * 4);
    unsigned short* wt_hi   = (unsigned short*)alloc((size_t)64 * KP * 2);
    unsigned short* wt_lo   = (unsigned short*)alloc((size_t)64 * KP * 2);
    size_t x16_bytes = (size_t)N * KP * 2;
    bool big_ws = (used + x16_bytes + 256 <= ws_size);
    unsigned short* x16 = big_ws ? (unsigned short*)alloc(x16_bytes) : nullptr;

    const int* src = ei;
    const int* dst = ei + E;

    hipMemsetAsync(counts, 0, (size_t)N * 4, stream);
    int ge = (E + 255) / 256;
    hist_kernel<<<ge, 256, 0, stream>>>(dst, counts, E);
    dinv_kernel<<<(N + 255) / 256, 256, 0, stream>>>(counts, dinv, N);
    scan_kernel<<<1, 1024, 0, stream>>>(counts, offsets, cursor, N);
    scatter_kernel<<<ge, 256, 0, stream>>>(src, dst, dinv, cursor, csr_src, csr_w, E);

    convert_w<<<(KP * 64 + 255) / 256, 256, 0, stream>>>(W1, wt_hi, wt_lo);
    if (big_ws) {
        convert_x<<<N, 256, 0, stream>>>(x, x16);
        gemm_xw_v3<<<(N + 127) / 128, 256, 0, stream>>>(x16, wt_hi, wt_lo, bufA, N);
    } else {
        gemm_xw_mfma<<<(N + 127) / 128, 256, 0, stream>>>(x, wt_hi, wt_lo, bufA, N);
    }
    aggregate_kernel<<<(N + 3) / 4, 256, 0, stream>>>(bufA, csr_src, csr_w, offsets, dinv, b1, bufB, N);
    gemm64_kernel<<<(N + 3) / 4, 256, 0, stream>>>(bufB, W2, bufA, N);
    aggregate_kernel<<<(N + 3) / 4, 256, 0, stream>>>(bufA, csr_src, csr_w, offsets, dinv, b2, bufB, N);
    mlp_kernel<<<(N + 3) / 4, 256, 0, stream>>>(bufB, Wf1, bf1, Wf2, bf2, Wf3, bf3, outp, N);
}

// Round 4
// 1295.921 us; speedup vs baseline: 1.1581x; 1.1581x over previous
//
#include <hip/hip_runtime.h>

#define N_NODES 100000
#define N_FEAT  1433
#define KP      1472     // padded K: 46*32
#define KLOOP   1440     // last non-empty k-step start+32 (covers 0..1439 >= 1433)
#define HID     64
#define NCLS    7

typedef __attribute__((ext_vector_type(8))) short short8v;
typedef __attribute__((ext_vector_type(4))) float f32x4;

__device__ __forceinline__ unsigned short f2bf(float v) {
    unsigned u = __float_as_uint(v);
    unsigned r = (u + 0x7FFFu + ((u >> 16) & 1u)) >> 16;   // RNE
    return (unsigned short)r;
}
__device__ __forceinline__ float bf2f(unsigned short h) {
    return __uint_as_float(((unsigned)h) << 16);
}

// ---------------- degree histogram ----------------
__global__ __launch_bounds__(256)
void hist_kernel(const int* __restrict__ dst, int* __restrict__ counts, int E) {
    int e = blockIdx.x * 256 + threadIdx.x;
    if (e < E) atomicAdd(&counts[dst[e]], 1);
}

__global__ __launch_bounds__(256)
void dinv_kernel(const int* __restrict__ counts, float* __restrict__ dinv, int n) {
    int i = blockIdx.x * 256 + threadIdx.x;
    if (i < n) dinv[i] = rsqrtf((float)(counts[i] + 1));   // +1 = self loop
}

// ---------------- single-block exclusive scan ----------------
__global__ __launch_bounds__(1024)
void scan_kernel(const int* __restrict__ counts, int* __restrict__ offsets,
                 int* __restrict__ cursor, int n) {
    __shared__ int sums[1024];
    int t = threadIdx.x;
    int chunk = (n + 1023) >> 10;
    int beg = t * chunk;
    int end = min(beg + chunk, n);
    int s = 0;
    for (int i = beg; i < end; ++i) s += counts[i];
    sums[t] = s;
    __syncthreads();
    for (int off = 1; off < 1024; off <<= 1) {
        int v = (t >= off) ? sums[t - off] : 0;
        __syncthreads();
        sums[t] += v;
        __syncthreads();
    }
    int run = (t == 0) ? 0 : sums[t - 1];
    for (int i = beg; i < end; ++i) {
        offsets[i] = run; cursor[i] = run;
        run += counts[i];
    }
    if (t == 1023) offsets[n] = run;
}

// ---------------- CSR scatter ----------------
__global__ __launch_bounds__(256)
void scatter_kernel(const int* __restrict__ src, const int* __restrict__ dst,
                    const float* __restrict__ dinv, int* __restrict__ cursor,
                    int* __restrict__ csr_src, float* __restrict__ csr_w, int E) {
    int e = blockIdx.x * 256 + threadIdx.x;
    if (e >= E) return;
    int s = src[e], d = dst[e];
    int pos = atomicAdd(&cursor[d], 1);
    csr_src[pos] = s;
    csr_w[pos]   = dinv[s] * dinv[d];
}

// ---------------- W1 transpose + bf16 hi/lo split: [1433,64] -> [64,KP] ----------------
__global__ __launch_bounds__(256)
void convert_w(const float* __restrict__ W,
               unsigned short* __restrict__ wt_hi, unsigned short* __restrict__ wt_lo) {
    int idx = blockIdx.x * 256 + threadIdx.x;   // over KP*64
    if (idx >= KP * 64) return;
    int k = idx >> 6, n = idx & 63;
    float v = (k < N_FEAT) ? W[(size_t)k * 64 + n] : 0.f;
    unsigned short h = f2bf(v);
    wt_hi[(size_t)n * KP + k] = h;
    wt_lo[(size_t)n * KP + k] = f2bf(v - bf2f(h));
}

// load 8 f32 from a (4B-aligned) row, convert to bf16 fragment
__device__ __forceinline__ short8v load_frag_f32(const float* __restrict__ row, int kk) {
    short8v r;
    if (kk + 8 <= N_FEAT) {
        float v[8];
        __builtin_memcpy(v, row + kk, 32);   // align-4 vector load
#pragma unroll
        for (int j = 0; j < 8; ++j) r[j] = (short)f2bf(v[j]);
    } else {
#pragma unroll
        for (int j = 0; j < 8; ++j)
            r[j] = (short)((kk + j < N_FEAT) ? f2bf(row[kk + j]) : (unsigned short)0);
    }
    return r;
}

// ---------------- GEMM1 v4: X f32 direct, in-register bf16, no LDS/barriers ----------------
// wave owns 32 rows (2x16). A: lane(q,r) holds row r, k-slice q*8..+8.
// B direct from L2-resident wt_hi/wt_lo. Output bf16.
__global__ __launch_bounds__(256)
void gemm_xw_v4(const float* __restrict__ X,
                const unsigned short* __restrict__ wt_hi,
                const unsigned short* __restrict__ wt_lo,
                unsigned short* __restrict__ H16, int M) {
    const int t    = threadIdx.x;
    const int lane = t & 63;
    const int w    = t >> 6;
    const int m0   = blockIdx.x * 128 + w * 32;
    const int lrow = lane & 15;
    const int koff = (lane >> 4) * 8;

    f32x4 acc[2][4];
#pragma unroll
    for (int i = 0; i < 2; ++i)
#pragma unroll
        for (int j = 0; j < 4; ++j) acc[i][j] = (f32x4){0.f, 0.f, 0.f, 0.f};

    const float* a0 = X + (size_t)min(m0 + lrow,      M - 1) * N_FEAT;
    const float* a1 = X + (size_t)min(m0 + 16 + lrow, M - 1) * N_FEAT;
    const unsigned short* bh = wt_hi + (size_t)lrow * KP + koff;
    const unsigned short* bl = wt_lo + (size_t)lrow * KP + koff;

#pragma unroll 2
    for (int k = 0; k < KLOOP; k += 32) {
        int kk = k + koff;
        short8v aH[2], bH[4], bL[4];
        aH[0] = load_frag_f32(a0, kk);
        aH[1] = load_frag_f32(a1, kk);
#pragma unroll
        for (int nf = 0; nf < 4; ++nf) {
            bH[nf] = *(const short8v*)(bh + (size_t)nf * 16 * KP + k);
            bL[nf] = *(const short8v*)(bl + (size_t)nf * 16 * KP + k);
        }
#pragma unroll
        for (int mf = 0; mf < 2; ++mf)
#pragma unroll
            for (int nf = 0; nf < 4; ++nf) {
                acc[mf][nf] = __builtin_amdgcn_mfma_f32_16x16x32_bf16(aH[mf], bH[nf], acc[mf][nf], 0, 0, 0);
                acc[mf][nf] = __builtin_amdgcn_mfma_f32_16x16x32_bf16(aH[mf], bL[nf], acc[mf][nf], 0, 0, 0);
            }
    }
    // C: col = lane&15, row = (lane>>4)*4 + reg
#pragma unroll
    for (int mf = 0; mf < 2; ++mf)
#pragma unroll
        for (int r = 0; r < 4; ++r) {
            int row = m0 + mf * 16 + ((lane >> 4) << 2) + r;
            if (row < M) {
#pragma unroll
                for (int nf = 0; nf < 4; ++nf)
                    H16[(size_t)row * 64 + nf * 16 + lrow] = f2bf(acc[mf][nf][r]);
            }
        }
}

// ---------------- GEMM2: [M,64] f32 @ [64,64] via MFMA, W in swizzled LDS ----------------
__global__ __launch_bounds__(256)
void gemm_hid(const float* __restrict__ A, const float* __restrict__ W,
              unsigned short* __restrict__ H16, int M) {
    __shared__ __align__(16) unsigned short WsH[64 * 64];
    __shared__ __align__(16) unsigned short WsL[64 * 64];
    char* wsH = (char*)WsH; char* wsL = (char*)WsL;
    const int t = threadIdx.x;
#pragma unroll
    for (int p = 0; p < 16; ++p) {
        int id = p * 256 + t;           // 0..4095
        int k = id >> 6, n = id & 63;
        float v = W[id];
        unsigned short h = f2bf(v);
        int byte = (n * 128 + k * 2) ^ ((n & 7) << 4);
        *(unsigned short*)(wsH + byte) = h;
        *(unsigned short*)(wsL + byte) = f2bf(v - bf2f(h));
    }
    __syncthreads();

    const int lane = t & 63;
    const int w    = t >> 6;
    const int m0   = blockIdx.x * 128 + w * 32;
    const int lrow = lane & 15;
    const int koff = (lane >> 4) * 8;

    const float* a0 = A + (size_t)min(m0 + lrow,      M - 1) * 64;
    const float* a1 = A + (size_t)min(m0 + 16 + lrow, M - 1) * 64;

    f32x4 acc[2][4];
#pragma unroll
    for (int i = 0; i < 2; ++i)
#pragma unroll
        for (int j = 0; j < 4; ++j) acc[i][j] = (f32x4){0.f, 0.f, 0.f, 0.f};

#pragma unroll
    for (int k = 0; k < 64; k += 32) {
        int kk = k + koff;
        short8v aH[2], bH[4], bL[4];
        float v0[8], v1[8];
        __builtin_memcpy(v0, a0 + kk, 32);   // rows are 256B-aligned
        __builtin_memcpy(v1, a1 + kk, 32);
#pragma unroll
        for (int j = 0; j < 8; ++j) {
            aH[0][j] = (short)f2bf(v0[j]);
            aH[1][j] = (short)f2bf(v1[j]);
        }
#pragma unroll
        for (int nf = 0; nf < 4; ++nf) {
            int n = nf * 16 + lrow;
            int byte = (n * 128 + kk * 2) ^ ((n & 7) << 4);
            bH[nf] = *(const short8v*)(wsH + byte);
            bL[nf] = *(const short8v*)(wsL + byte);
        }
#pragma unroll
        for (int mf = 0; mf < 2; ++mf)
#pragma unroll
            for (int nf = 0; nf < 4; ++nf) {
                acc[mf][nf] = __builtin_amdgcn_mfma_f32_16x16x32_bf16(aH[mf], bH[nf], acc[mf][nf], 0, 0, 0);
                acc[mf][nf] = __builtin_amdgcn_mfma_f32_16x16x32_bf16(aH[mf], bL[nf], acc[mf][nf], 0, 0, 0);
            }
    }
#pragma unroll
    for (int mf = 0; mf < 2; ++mf)
#pragma unroll
        for (int r = 0; r < 4; ++r) {
            int row = m0 + mf * 16 + ((lane >> 4) << 2) + r;
            if (row < M) {
#pragma unroll
                for (int nf = 0; nf < 4; ++nf)
                    H16[(size_t)row * 64 + nf * 16 + lrow] = f2bf(acc[mf][nf][r]);
            }
        }
}

// ---------------- gather-aggregate: bf16 h, one wave per node, lane = feature ----------------
__global__ __launch_bounds__(256)
void aggregate_kernel(const unsigned short* __restrict__ h16, const int* __restrict__ csr_src,
                      const float* __restrict__ csr_w, const int* __restrict__ offsets,
                      const float* __restrict__ dinv, const float* __restrict__ bias,
                      float* __restrict__ out, int n) {
    int wave = (blockIdx.x * blockDim.x + threadIdx.x) >> 6;
    int lane = threadIdx.x & 63;
    if (wave >= n) return;
    float di  = dinv[wave];
    float acc = bf2f(h16[(size_t)wave * HID + lane]) * di * di;   // self loop
    int e = offsets[wave], end = offsets[wave + 1];
    for (; e + 4 <= end; e += 4) {                                // 4-deep load pipeline
        int   s0 = csr_src[e],   s1 = csr_src[e+1], s2 = csr_src[e+2], s3 = csr_src[e+3];
        float w0 = csr_w[e],     w1 = csr_w[e+1],   w2 = csr_w[e+2],   w3 = csr_w[e+3];
        float h0 = bf2f(h16[(size_t)s0 * HID + lane]);
        float h1 = bf2f(h16[(size_t)s1 * HID + lane]);
        float h2 = bf2f(h16[(size_t)s2 * HID + lane]);
        float h3 = bf2f(h16[(size_t)s3 * HID + lane]);
        acc = fmaf(h0, w0, acc); acc = fmaf(h1, w1, acc);
        acc = fmaf(h2, w2, acc); acc = fmaf(h3, w3, acc);
    }
    for (; e < end; ++e)
        acc = fmaf(bf2f(h16[(size_t)csr_src[e] * HID + lane]), csr_w[e], acc);
    out[(size_t)wave * HID + lane] = fmaxf(acc + bias[lane], 0.f);
}

// ---------------- fused MLP head + log_softmax: wave per node ----------------
__global__ __launch_bounds__(256)
void mlp_kernel(const float* __restrict__ y,
                const float* __restrict__ Wf1, const float* __restrict__ bf1,
                const float* __restrict__ Wf2, const float* __restrict__ bf2,
                const float* __restrict__ Wf3, const float* __restrict__ bf3,
                float* __restrict__ out, int M) {
    __shared__ float W1s[64 * 64];
    __shared__ float W2s[64 * 64];
    __shared__ float W3s[64 * NCLS];
    __shared__ float b1s[64], b2s[64], b3s[NCLS];
    __shared__ float vbuf[4][64];
    __shared__ float zbuf[4][8];
    int tid = threadIdx.x;
    for (int i = tid; i < 4096; i += 256) { W1s[i] = Wf1[i]; W2s[i] = Wf2[i]; }
    for (int i = tid; i < 64 * NCLS; i += 256) W3s[i] = Wf3[i];
    if (tid < 64) { b1s[tid] = bf1[tid]; b2s[tid] = bf2[tid]; }
    if (tid < NCLS) b3s[tid] = bf3[tid];
    __syncthreads();
    int w = tid >> 6, lane = tid & 63;
    int node = blockIdx.x * 4 + w;
    if (node >= M) return;

    vbuf[w][lane] = y[(size_t)node * 64 + lane];
    float u = b1s[lane];
#pragma unroll
    for (int k = 0; k < 64; ++k) u = fmaf(vbuf[w][k], W1s[k * 64 + lane], u);
    u = fmaxf(u, 0.f);
    vbuf[w][lane] = u;
    float u2 = b2s[lane];
#pragma unroll
    for (int k = 0; k < 64; ++k) u2 = fmaf(vbuf[w][k], W2s[k * 64 + lane], u2);
    u2 = fmaxf(u2, 0.f);
    vbuf[w][lane] = u2;
    float z = 0.f;
    if (lane < NCLS) {
        z = b3s[lane];
#pragma unroll
        for (int k = 0; k < 64; ++k) z = fmaf(vbuf[w][k], W3s[k * NCLS + lane], z);
    }
    if (lane < 8)    zbuf[w][lane] = -1e30f;
    if (lane < NCLS) zbuf[w][lane] = z;
    float m = -1e30f;
#pragma unroll
    for (int j = 0; j < NCLS; ++j) m = fmaxf(m, zbuf[w][j]);
    float ssum = 0.f;
#pragma unroll
    for (int j = 0; j < NCLS; ++j) ssum += expf(zbuf[w][j] - m);
    float lse = m + logf(ssum);
    if (lane < NCLS) out[(size_t)node * NCLS + lane] = z - lse;
}

extern "C" void kernel_launch(void* const* d_in, const int* in_sizes, int n_in,
                              void* d_out, int out_size, void* d_ws, size_t ws_size,
                              hipStream_t stream) {
    const float* x   = (const float*)d_in[0];
    const int*   ei  = (const int*)d_in[1];
    const float* W1  = (const float*)d_in[2];
    const float* b1  = (const float*)d_in[3];
    const float* W2  = (const float*)d_in[4];
    const float* b2  = (const float*)d_in[5];
    const float* Wf1 = (const float*)d_in[6];
    const float* bf1 = (const float*)d_in[7];
    const float* Wf2 = (const float*)d_in[8];
    const float* bf2 = (const float*)d_in[9];
    const float* Wf3 = (const float*)d_in[10];
    const float* bf3 = (const float*)d_in[11];

    const int N = N_NODES;
    const int E = in_sizes[1] / 2;
    float* outp = (float*)d_out;

    char* p = (char*)d_ws;
    auto alloc = [&](size_t bytes) {
        char* q = p;
        p += (bytes + 255) & ~(size_t)255;
        return q;
    };
    int*            counts  = (int*)           alloc((size_t)N * 4);
    int*            offsets = (int*)           alloc((size_t)(N + 1) * 4);
    int*            cursor  = (int*)           alloc((size_t)N * 4);
    float*          dinv    = (float*)         alloc((size_t)N * 4);
    int*            csr_src = (int*)           alloc((size_t)E * 4);
    float*          csr_w   = (float*)         alloc((size_t)E * 4);
    unsigned short* wt_hi   = (unsigned short*)alloc((size_t)64 * KP * 2);
    unsigned short* wt_lo   = (unsigned short*)alloc((size_t)64 * KP * 2);
    unsigned short* bufH16  = (unsigned short*)alloc((size_t)N * HID * 2);
    float*          bufF    = (float*)         alloc((size_t)N * HID * 4);

    const int* src = ei;
    const int* dst = ei + E;

    hipMemsetAsync(counts, 0, (size_t)N * 4, stream);
    int ge = (E + 255) / 256;
    hist_kernel<<<ge, 256, 0, stream>>>(dst, counts, E);
    dinv_kernel<<<(N + 255) / 256, 256, 0, stream>>>(counts, dinv, N);
    scan_kernel<<<1, 1024, 0, stream>>>(counts, offsets, cursor, N);
    scatter_kernel<<<ge, 256, 0, stream>>>(src, dst, dinv, cursor, csr_src, csr_w, E);
    convert_w<<<(KP * 64 + 255) / 256, 256, 0, stream>>>(W1, wt_hi, wt_lo);

    // layer 1
    gemm_xw_v4<<<(N + 127) / 128, 256, 0, stream>>>(x, wt_hi, wt_lo, bufH16, N);
    aggregate_kernel<<<(N + 3) / 4, 256, 0, stream>>>(bufH16, csr_src, csr_w, offsets, dinv, b1, bufF, N);
    // layer 2
    gemm_hid<<<(N + 127) / 128, 256, 0, stream>>>(bufF, W2, bufH16, N);
    aggregate_kernel<<<(N + 3) / 4, 256, 0, stream>>>(bufH16, csr_src, csr_w, offsets, dinv, b2, bufF, N);
    // head
    mlp_kernel<<<(N + 3) / 4, 256, 0, stream>>>(bufF, Wf1, bf1, Wf2, bf2, Wf3, bf3, outp, N);
}